// Round 3
// baseline (343.717 us; speedup 1.0000x reference)
//
#include <hip/hip_runtime.h>

// ---- transpose: x viewed as [bi=512][c=2048] -> xt3[c][bi]  (bi = b*8+i) ----
__global__ __launch_bounds__(256) void transpose_kernel(const float* __restrict__ x,
                                                        float* __restrict__ xt3) {
    __shared__ float tile[64][65];
    const int bi0 = (blockIdx.x >> 5) << 6;    // 8 bi-tiles
    const int c0  = (blockIdx.x & 31) << 6;    // 32 c-tiles
    const int tx = threadIdx.x & 63, ty = threadIdx.x >> 6;
#pragma unroll
    for (int p = 0; p < 16; ++p)
        tile[ty + p * 4][tx] = x[(size_t)(bi0 + ty + p * 4) * 2048 + c0 + tx];
    __syncthreads();
#pragma unroll
    for (int p = 0; p < 16; ++p)
        xt3[(size_t)(c0 + ty + p * 4) * 512 + bi0 + tx] = tile[tx][ty + p * 4];
}

// ---- softmax over u per c ----
__global__ __launch_bounds__(256) void softmax_kernel(const float* __restrict__ bij,
                                                      float* __restrict__ cij) {
    int c = blockIdx.x * 256 + threadIdx.x;     // grid = 8
    float vals[32];
    float m = -1e30f;
#pragma unroll
    for (int u = 0; u < 32; ++u) { vals[u] = bij[c * 32 + u]; m = fmaxf(m, vals[u]); }
    float ssum = 0.f;
#pragma unroll
    for (int u = 0; u < 32; ++u) { vals[u] = expf(vals[u] - m); ssum += vals[u]; }
    float inv = 1.f / ssum;
#pragma unroll
    for (int u = 0; u < 32; ++u) cij[c * 32 + u] = vals[u] * inv;
}

// ---- s-pass: lane = b. part[chunk][u][d][b] = sum_{c in chunk} cij[c,u]*uh[b,d]
// grid = 32 u * 32 chunks ; block 256 = 4 waves ; wave handles 16 c's.
// W + cij loads are wave-uniform (broadcast); x is per-lane float4 pair.
template <int UNIFORM>
__global__ __launch_bounds__(256, 4) void s_kernel3(const float* __restrict__ xt3,
                                                    const float* __restrict__ W,
                                                    const float* __restrict__ cij,
                                                    float* __restrict__ part) {
    const int u     = blockIdx.x >> 5;
    const int chunk = blockIdx.x & 31;
    const int t = threadIdx.x, w = t >> 6, l = t & 63;

    float acc[16];
#pragma unroll
    for (int d = 0; d < 16; ++d) acc[d] = 0.f;

    const int cbase = chunk * 64;
#pragma unroll 2
    for (int j = 0; j < 16; ++j) {
        const int c = cbase + j * 4 + w;
        const float4* xp = reinterpret_cast<const float4*>(xt3 + (size_t)c * 512 + l * 8);
        const float4 xa = xp[0], xb = xp[1];
        const float cw = UNIFORM ? 0.03125f : cij[c * 32 + u];
        const float4* Wp = reinterpret_cast<const float4*>(W + ((size_t)c * 32 + u) * 128);
        float uh[16];
#pragma unroll
        for (int q = 0; q < 8; ++q) {
            const float4 w0 = Wp[q * 4 + 0], w1 = Wp[q * 4 + 1];
            const float4 w2 = Wp[q * 4 + 2], w3 = Wp[q * 4 + 3];
            uh[2 * q]     = w0.x * xa.x + w0.y * xa.y + w0.z * xa.z + w0.w * xa.w
                          + w1.x * xb.x + w1.y * xb.y + w1.z * xb.z + w1.w * xb.w;
            uh[2 * q + 1] = w2.x * xa.x + w2.y * xa.y + w2.z * xa.z + w2.w * xa.w
                          + w3.x * xb.x + w3.y * xb.y + w3.z * xb.z + w3.w * xb.w;
        }
#pragma unroll
        for (int d = 0; d < 16; ++d) acc[d] += cw * uh[d];
    }

    // cross-wave reduce (stride 17: conflict-free)
    __shared__ float red[4][64][17];
#pragma unroll
    for (int d = 0; d < 16; ++d) red[w][l][d] = acc[d];
    __syncthreads();
    const int l2 = t & 63, dg = t >> 6;
#pragma unroll
    for (int k = 0; k < 4; ++k) {
        const int d = dg * 4 + k;
        float a = red[0][l2][d] + red[1][l2][d] + red[2][l2][d] + red[3][l2][d];
        part[(((size_t)chunk * 32 + u) * 16 + d) * 64 + l2] = a;
    }
}

// ---- s[u][d][b] = sum_chunk part[chunk][u][d][b] ----
__global__ __launch_bounds__(256) void reduce_kernel(const float* __restrict__ part,
                                                     float* __restrict__ s) {
    int n = blockIdx.x * 256 + threadIdx.x;     // grid = 128
    float a = 0.f;
#pragma unroll
    for (int k = 0; k < 32; ++k) a += part[k * 32768 + n];
    s[n] = a;
}

// ---- squash (reference quirk: mag over U per (b,d)); s layout [u][d][b] ----
__global__ __launch_bounds__(256) void v_kernel2(const float* __restrict__ s,
                                                 float* __restrict__ v,
                                                 float* __restrict__ out) {
    int n = blockIdx.x * 256 + threadIdx.x;     // grid = 4 -> 1024 = B*D
    int b = n >> 4, d = n & 15;
    float sv[32];
    float msq = 0.f;
#pragma unroll
    for (int u = 0; u < 32; ++u) {
        sv[u] = s[(u * 16 + d) * 64 + b];
        msq += sv[u] * sv[u];
    }
    float scale = msq / ((1.f + msq) * sqrtf(msq));
#pragma unroll
    for (int u = 0; u < 32; ++u) {
        float val = sv[u] * scale;
        v[(b * 32 + u) * 16 + d] = val;
        out[(b * 32 + u) * 16 + d] = val;
    }
}

// ---- delta: bij[c,u] (=|+=) (1/B) sum_{b,d} uh[b,c,u,d]*v[b,u,d] ----
// grid = C ; block 256 ; lane: u = t>>3, d-pair = (t&7)*2
template <int FIRST>
__global__ __launch_bounds__(256) void delta_kernel(const float* __restrict__ xt3,
                                                    const float* __restrict__ W,
                                                    const float* __restrict__ v,
                                                    float* __restrict__ bij) {
    const int c = blockIdx.x;
    const int t = threadIdx.x;
    const int u = t >> 3;
    const int d0 = (t & 7) * 2;

    __shared__ float xs[512];                   // xt3 row already [b][i]
    xs[t] = xt3[(size_t)c * 512 + t];
    xs[t + 256] = xt3[(size_t)c * 512 + t + 256];
    __syncthreads();

    const float4* Wp = reinterpret_cast<const float4*>(W + ((size_t)c * 32 + u) * 128 + d0 * 8);
    const float4 w00 = Wp[0], w01 = Wp[1], w10 = Wp[2], w11 = Wp[3];

    float partial = 0.f;
#pragma unroll 4
    for (int b = 0; b < 64; ++b) {
        const float4 xa = *reinterpret_cast<const float4*>(&xs[b * 8]);
        const float4 xb = *reinterpret_cast<const float4*>(&xs[b * 8 + 4]);
        float uh0 = w00.x * xa.x + w00.y * xa.y + w00.z * xa.z + w00.w * xa.w
                  + w01.x * xb.x + w01.y * xb.y + w01.z * xb.z + w01.w * xb.w;
        float uh1 = w10.x * xa.x + w10.y * xa.y + w10.z * xa.z + w10.w * xa.w
                  + w11.x * xb.x + w11.y * xb.y + w11.z * xb.z + w11.w * xb.w;
        const float2 vv = *reinterpret_cast<const float2*>(v + ((size_t)(b * 32 + u) * 16 + d0));
        partial += uh0 * vv.x + uh1 * vv.y;
    }
    partial += __shfl_xor(partial, 1);
    partial += __shfl_xor(partial, 2);
    partial += __shfl_xor(partial, 4);
    if ((t & 7) == 0) {
        const float r = partial * (1.0f / 64.0f);
        if (FIRST) bij[c * 32 + u] = r;
        else       bij[c * 32 + u] += r;
    }
}

extern "C" void kernel_launch(void* const* d_in, const int* in_sizes, int n_in,
                              void* d_out, int out_size, void* d_ws, size_t ws_size,
                              hipStream_t stream) {
    const float* x = (const float*)d_in[0];   // (B, I, C) = (64, 8, 2048)
    const float* W = (const float*)d_in[1];   // (C, U, D, I) = (2048, 32, 16, 8)
    float* out = (float*)d_out;               // (B, U, D, 1) flat = 32768 fp32

    float* ws   = (float*)d_ws;
    float* xt3  = ws;                   // C*B*I    = 1,048,576 floats  [c][b][i]
    float* bij  = xt3 + 1048576;        // C*U      = 65,536
    float* cij  = bij + 65536;          // C*U      = 65,536
    float* s    = cij + 65536;          // U*D*B    = 32,768
    float* v    = s + 32768;            // B*U*D    = 32,768
    float* part = v + 32768;            // 32*U*D*B = 1,048,576

    transpose_kernel<<<256, 256, 0, stream>>>(x, xt3);

    // it 0: bij = 0 -> cij uniform 1/32 ; delta writes bij
    s_kernel3<1><<<1024, 256, 0, stream>>>(xt3, W, cij, part);
    reduce_kernel<<<128, 256, 0, stream>>>(part, s);
    v_kernel2<<<4, 256, 0, stream>>>(s, v, out);
    delta_kernel<1><<<2048, 256, 0, stream>>>(xt3, W, v, bij);

    // it 1
    softmax_kernel<<<8, 256, 0, stream>>>(bij, cij);
    s_kernel3<0><<<1024, 256, 0, stream>>>(xt3, W, cij, part);
    reduce_kernel<<<128, 256, 0, stream>>>(part, s);
    v_kernel2<<<4, 256, 0, stream>>>(s, v, out);
    delta_kernel<0><<<2048, 256, 0, stream>>>(xt3, W, v, bij);

    // it 2
    softmax_kernel<<<8, 256, 0, stream>>>(bij, cij);
    s_kernel3<0><<<1024, 256, 0, stream>>>(xt3, W, cij, part);
    reduce_kernel<<<128, 256, 0, stream>>>(part, s);
    v_kernel2<<<4, 256, 0, stream>>>(s, v, out);
}